// Round 6
// baseline (315.219 us; speedup 1.0000x reference)
//
#include <hip/hip_runtime.h>

#define NSEG 512
#define NSPLIT 32

typedef __attribute__((ext_vector_type(8))) short short8;
typedef __attribute__((ext_vector_type(4))) short short4v;
typedef __attribute__((ext_vector_type(4))) float floatx4;

// ws layout (bytes), all 16B-aligned
#define WS_WAT   0        // short [256][32]   WA^T
#define WS_WBT2  16384    // short [256][64]   WB^T (K padded 48->64 w/ zeros)
#define WS_W2GA  49152    // short [256][256]  (gA*Wback)^T
#define WS_W2GB  180224   // short [256][256]  (gB*Wback)^T
#define WS_C1A   311296   // float[256] gA . Wback[:,n]
#define WS_C2A   312320   // float[256] betaA . Wback[:,n] + bback
#define WS_C1B   313344
#define WS_C2B   314368
#define WS_INVA  315392   // float[32]  1/stdA
#define WS_INVB  315520   // float[48]  1/stdB
#define WS_VPART 315712   // float [NSPLIT][NSEG]
#define WS_CPART 381248   // float [NSPLIT][NSEG]
#define WS_NF    446848   // bf16 normalized feats (A then B), if ws_size permits

__device__ __forceinline__ short f2bf(float f) {  // RNE
  unsigned u = __builtin_bit_cast(unsigned, f);
  u += 0x7FFFu + ((u >> 16) & 1u);
  return (short)(u >> 16);
}

// ---- merged prep + norm: one launch. Tables/c1c2/zeroing ride along with the
// streaming normalization (norm dominates; prep work is ~7% extra chunks).
__global__ __launch_bounds__(256) void prep_norm_kernel(
    const float* __restrict__ fA, const float* __restrict__ fB,
    const float* __restrict__ mA, const float* __restrict__ mB,
    const float* __restrict__ sA, const float* __restrict__ sB,
    const float* __restrict__ WA, const float* __restrict__ WB,
    const float* __restrict__ Wback,
    const float* __restrict__ gA, const float* __restrict__ betaA,
    const float* __restrict__ gB, const float* __restrict__ betaB,
    const float* __restrict__ bback,
    char* __restrict__ ws, short* __restrict__ nfA, short* __restrict__ nfB,
    int rowsApad, int nA, int rowsBpad, int nB)
{
  __shared__ float sinv[80];            // [0:32) 1/stdA, [32:80) 1/stdB
  if (threadIdx.x < 32) sinv[threadIdx.x] = 1.0f / sA[threadIdx.x];
  else if (threadIdx.x < 80) sinv[threadIdx.x] = 1.0f / sB[threadIdx.x - 32];
  __syncthreads();
  const float* invAl = sinv;
  const float* invBl = sinv + 32;

  int tid = blockIdx.x * blockDim.x + threadIdx.x;
  int stride = gridDim.x * blockDim.x;

  // c1/c2 (blocks 0..3, one coefficient vector each; overlapped with norm on other blocks)
  if (blockIdx.x < 4) {
    int n = threadIdx.x;
    int which = blockIdx.x;
    const float* coef = (which == 0) ? gA : (which == 1) ? betaA : (which == 2) ? gB : betaB;
    float a = 0.f;
    #pragma unroll 8
    for (int k = 0; k < 256; k++) a = fmaf(coef[k], Wback[k*256 + n], a);
    float* dst = (float*)(ws + ((which == 0) ? WS_C1A : (which == 1) ? WS_C2A
                               : (which == 2) ? WS_C1B : WS_C2B));
    dst[n] = a + ((which & 1) ? bback[n] : 0.0f);
  }

  // small tables + zeroing (grid-stride)
  {
    short* waT  = (short*)(ws + WS_WAT);
    short* wbT2 = (short*)(ws + WS_WBT2);
    short* w2gA = (short*)(ws + WS_W2GA);
    short* w2gB = (short*)(ws + WS_W2GB);
    float* invA = (float*)(ws + WS_INVA);
    float* invB = (float*)(ws + WS_INVB);
    float* vz   = (float*)(ws + WS_VPART);
    if (tid < 32) invA[tid] = invAl[tid];
    if (tid < 48) invB[tid] = invBl[tid];
    for (int i = tid; i < 32*256; i += stride) {          // waT[n][k] = WA[k][n]
      int n = i >> 5, k = i & 31;
      waT[i] = f2bf(WA[k*256 + n]);
    }
    for (int i = tid; i < 256*64; i += stride) {          // wbT2[n][k] = WB[k][n], pad K
      int n = i >> 6, k = i & 63;
      wbT2[i] = (k < 48) ? f2bf(WB[k*256 + n]) : (short)0;
    }
    for (int i = tid; i < 256*256; i += stride) {         // w2g[n][k] = g[k]*Wback[k][n]
      int n = i >> 8, k = i & 255;
      float w = Wback[k*256 + n];
      w2gA[i] = f2bf(gA[k] * w);
      w2gB[i] = f2bf(gB[k] * w);
    }
    for (int i = tid; i < 2*NSPLIT*NSEG; i += stride) vz[i] = 0.0f;
  }

  // streaming normalization: nf = bf16(clamp((x-mean)*inv)), zero-padded
  int chunksA = rowsApad * 4;   // 4 x 8-elem chunks per 32-wide row
  int chunksB = rowsBpad * 8;   // 8 x 8-elem chunks per 64-wide row
  for (int i = tid; i < chunksA + chunksB; i += stride) {
    short8 o = {0,0,0,0,0,0,0,0};
    if (i < chunksA) {
      int row = i >> 2, c0 = (i & 3) * 8;
      if (row < nA) {
        const float* fp = fA + (size_t)row*32 + c0;
        floatx4 x0 = *(const floatx4*)fp;
        floatx4 x1 = *(const floatx4*)(fp + 4);
        floatx4 mv0 = *(const floatx4*)(mA + c0);
        floatx4 mv1 = *(const floatx4*)(mA + c0 + 4);
        floatx4 iv0 = *(const floatx4*)(invAl + c0);
        floatx4 iv1 = *(const floatx4*)(invAl + c0 + 4);
        #pragma unroll
        for (int e = 0; e < 4; e++) {
          float h0 = fminf(fmaxf((x0[e] - mv0[e]) * iv0[e], -5.0f), 5.0f);
          float h1 = fminf(fmaxf((x1[e] - mv1[e]) * iv1[e], -5.0f), 5.0f);
          o[e] = f2bf(h0);  o[4+e] = f2bf(h1);
        }
      }
      *(short8*)(nfA + (size_t)row*32 + c0) = o;
    } else {
      int j = i - chunksA;
      int row = j >> 3, c0 = (j & 7) * 8;
      if (row < nB && c0 < 48) {
        const float* fp = fB + (size_t)row*48 + c0;
        floatx4 x0 = *(const floatx4*)fp;
        floatx4 x1 = *(const floatx4*)(fp + 4);
        floatx4 mv0 = *(const floatx4*)(mB + c0);
        floatx4 mv1 = *(const floatx4*)(mB + c0 + 4);
        floatx4 iv0 = *(const floatx4*)(invBl + c0);
        floatx4 iv1 = *(const floatx4*)(invBl + c0 + 4);
        #pragma unroll
        for (int e = 0; e < 4; e++) {
          float h0 = fminf(fmaxf((x0[e] - mv0[e]) * iv0[e], -5.0f), 5.0f);
          float h1 = fminf(fmaxf((x1[e] - mv1[e]) * iv1[e], -5.0f), 5.0f);
          o[e] = f2bf(h0);  o[4+e] = f2bf(h1);
        }
      }
      *(short8*)(nfB + (size_t)row*64 + c0) = o;
    }
  }
}

// ---- per-entity-type tile body; KSTR/KSTEPS compile-time so ALL GEMM loads are
// base-pointer + literal offset (no per-iteration 64-bit address VALU).
// Operand-swapped MFMA: lane's 4 acc regs = 4 consecutive cols of one row:
// row = 16*mt + l15, col = 64*wave + 16*nt + 4*quad + r.
template <int KSTR, int KSTEPS>
__device__ __forceinline__ void tile_body(
    const short* __restrict__ nfb,      // nf + r0*KSTR
    const short* __restrict__ weT, const short* __restrict__ w2gT,
    const float* __restrict__ biasp, const float* __restrict__ c1p,
    const float* __restrict__ c2p, const float* __restrict__ Wv,
    const int* __restrict__ bidx, float* __restrict__ vpart, float* __restrict__ cpart,
    short* ztile, float (*sred)[4], float (*s2red)[4], float (*vpw)[4],
    int valid, int gbase, int split, int tid)
{
  const int wave = tid >> 6;
  const int lane = tid & 63;
  const int l15  = lane & 15;
  const int quad = lane >> 4;

  // ---- GEMM1 ----
  floatx4 acc1[4][4];
  #pragma unroll
  for (int mt = 0; mt < 4; mt++)
    #pragma unroll
    for (int nt = 0; nt < 4; nt++)
      acc1[mt][nt] = 0.0f;

  const short* nfp = nfb + l15*KSTR + quad*8;
  const short* wep = weT + (64*wave + l15)*KSTR + quad*8;
  #pragma unroll
  for (int kk = 0; kk < KSTEPS; kk++) {
    short8 bfw[4];
    #pragma unroll
    for (int nt = 0; nt < 4; nt++)
      bfw[nt] = *(const short8*)(wep + nt*16*KSTR + kk*32);
    #pragma unroll
    for (int mt = 0; mt < 4; mt++) {
      short8 a = *(const short8*)(nfp + mt*16*KSTR + kk*32);
      #pragma unroll
      for (int nt = 0; nt < 4; nt++)
        acc1[mt][nt] = __builtin_amdgcn_mfma_f32_16x16x32_bf16(bfw[nt], a, acc1[mt][nt], 0, 0, 0);
    }
  }

  // ---- epilogue1: relu(+b1) -> ztile (b64 packed) + per-row stats ----
  float sacc[4] = {0.f,0.f,0.f,0.f}, s2acc[4] = {0.f,0.f,0.f,0.f};
  {
    short* ztw = ztile + l15*264 + 64*wave + 4*quad;
    const float* bp = biasp + 64*wave + 4*quad;
    #pragma unroll
    for (int nt = 0; nt < 4; nt++) {
      floatx4 b1v = *(const floatx4*)(bp + 16*nt);
      #pragma unroll
      for (int mt = 0; mt < 4; mt++) {
        short4v pk;
        #pragma unroll
        for (int r = 0; r < 4; r++) {
          float h = fmaxf(acc1[mt][nt][r] + b1v[r], 0.0f);
          sacc[mt] += h;
          s2acc[mt] = fmaf(h, h, s2acc[mt]);
          pk[r] = f2bf(h);
        }
        *(short4v*)(ztw + mt*16*264 + nt*16) = pk;
      }
    }
  }
  #pragma unroll
  for (int mt = 0; mt < 4; mt++) {
    float s = sacc[mt], s2 = s2acc[mt];
    s += __shfl_xor(s, 16, 64);  s2 += __shfl_xor(s2, 16, 64);
    s += __shfl_xor(s, 32, 64);  s2 += __shfl_xor(s2, 32, 64);
    if (lane < 16) {
      sred[16*mt + lane][wave] = s;
      s2red[16*mt + lane][wave] = s2;
    }
  }
  __syncthreads();

  // ---- GEMM2: K=256, base+imm addressing, unroll 2 for prefetch depth ----
  floatx4 acc2[4][4];
  #pragma unroll
  for (int mt = 0; mt < 4; mt++)
    #pragma unroll
    for (int nt = 0; nt < 4; nt++)
      acc2[mt][nt] = 0.0f;

  const short* wgp = w2gT + (64*wave + l15)*256 + quad*8;
  const short* ztp = ztile + l15*264 + quad*8;
  #pragma unroll 2
  for (int kk = 0; kk < 8; kk++) {
    short8 bf[4];
    #pragma unroll
    for (int nt = 0; nt < 4; nt++)
      bf[nt] = *(const short8*)(wgp + nt*16*256 + kk*32);
    #pragma unroll
    for (int mt = 0; mt < 4; mt++) {
      short8 a = *(const short8*)(ztp + mt*16*264 + kk*32);
      #pragma unroll
      for (int nt = 0; nt < 4; nt++)
        acc2[mt][nt] = __builtin_amdgcn_mfma_f32_16x16x32_bf16(bf[nt], a, acc2[mt][nt], 0, 0, 0);
    }
  }

  // ---- LN scalars (deferred: recomputed AFTER GEMM2 so they're not live through it) ----
  float rsv[4], mrsv[4];
  #pragma unroll
  for (int mt = 0; mt < 4; mt++) {
    int row = 16*mt + l15;
    floatx4 sv  = *(const floatx4*)sred[row];
    floatx4 s2v = *(const floatx4*)s2red[row];
    float s  = sv[0] + sv[1] + sv[2] + sv[3];
    float s2 = s2v[0] + s2v[1] + s2v[2] + s2v[3];
    float mu  = s * (1.0f/256.0f);
    float var = fmaxf(s2 * (1.0f/256.0f) - mu*mu, 0.0f);
    float rs  = rsqrtf(var + 1e-5f);
    rsv[mt]  = rs;
    mrsv[mt] = mu * rs;
  }

  // ---- epilogue2: y = relu(rs*q - mu*rs*c1 + c2); v = y . Wv ----
  float pv[4] = {0.f, 0.f, 0.f, 0.f};
  {
    const float* c1b = c1p + 64*wave + 4*quad;
    const float* c2b = c2p + 64*wave + 4*quad;
    const float* wvb = Wv  + 64*wave + 4*quad;
    #pragma unroll
    for (int nt = 0; nt < 4; nt++) {
      floatx4 c1v = *(const floatx4*)(c1b + 16*nt);
      floatx4 c2v = *(const floatx4*)(c2b + 16*nt);
      floatx4 wvv = *(const floatx4*)(wvb + 16*nt);
      #pragma unroll
      for (int mt = 0; mt < 4; mt++) {
        float rs = rsv[mt], mrs = mrsv[mt];
        #pragma unroll
        for (int r = 0; r < 4; r++) {
          float t = fmaf(-mrs, c1v[r], c2v[r]);
          float y = fmaf(rs, acc2[mt][nt][r], t);
          y = fmaxf(y, 0.0f);
          pv[mt] = fmaf(y, wvv[r], pv[mt]);
        }
      }
    }
  }
  #pragma unroll
  for (int mt = 0; mt < 4; mt++) {
    float p = pv[mt];
    p += __shfl_xor(p, 16, 64);
    p += __shfl_xor(p, 32, 64);
    if (lane < 16) vpw[16*mt + lane][wave] = p;
  }
  __syncthreads();

  // ---- scatter ----
  if (tid < valid) {
    floatx4 vv = *(const floatx4*)vpw[tid];
    float v = vv[0] + vv[1] + vv[2] + vv[3];
    int seg = bidx[gbase + tid];
    atomicAdd(&vpart[split*NSEG + seg], v);
    atomicAdd(&cpart[split*NSEG + seg], 1.0f);
  }
}

template <bool PRE>
__global__ __launch_bounds__(256, 4) void fused_kernel(
    const float* __restrict__ featsA, const float* __restrict__ featsB,
    const short* __restrict__ nfA, const short* __restrict__ nfB,
    const float* __restrict__ mA, const float* __restrict__ mB,
    const float* __restrict__ bA, const float* __restrict__ bB,
    const float* __restrict__ Wv, const int* __restrict__ bidx,
    const char* __restrict__ ws, float* __restrict__ vpart, float* __restrict__ cpart,
    int tilesA, int nA, int nB)
{
  __shared__ __attribute__((aligned(16))) short ztile[64*264];   // h, bf16, stride 264
  __shared__ __attribute__((aligned(16))) float sred[64][4];
  __shared__ __attribute__((aligned(16))) float s2red[64][4];
  __shared__ __attribute__((aligned(16))) float vpw[64][4];

  const int tid  = threadIdx.x;
  const bool isA = (blockIdx.x < (unsigned)tilesA);
  const int  tb  = isA ? blockIdx.x : (blockIdx.x - tilesA);
  const int  r0  = tb * 64;
  const int  nrows = isA ? nA : nB;
  const int  valid = min(64, nrows - r0);
  const int  gbase = (isA ? r0 : (nA + r0));
  const int  split = blockIdx.x & (NSPLIT - 1);
  const float* biasp = isA ? bA : bB;
  const short* weT   = (const short*)(ws + (isA ? WS_WAT : WS_WBT2));
  const short* w2gT  = (const short*)(ws + (isA ? WS_W2GA : WS_W2GB));
  const float* c1p   = (const float*)(ws + (isA ? WS_C1A : WS_C1B));
  const float* c2p   = (const float*)(ws + (isA ? WS_C2A : WS_C2B));

  if (PRE) {
    if (isA)
      tile_body<32,1>(nfA + (size_t)r0*32, weT, w2gT, biasp, c1p, c2p, Wv,
                      bidx, vpart, cpart, ztile, sred, s2red, vpw,
                      valid, gbase, split, tid);
    else
      tile_body<64,2>(nfB + (size_t)r0*64, weT, w2gT, biasp, c1p, c2p, Wv,
                      bidx, vpart, cpart, ztile, sred, s2red, vpw,
                      valid, gbase, split, tid);
    return;
  }

  // -------- fallback (no prenorm workspace): round-3-verified path --------
  const int wave = tid >> 6;
  const int lane = tid & 63;
  const int l15  = lane & 15;
  const int quad = lane >> 4;
  const float* feats = isA ? featsA : featsB;
  const float* meanp = isA ? mA : mB;
  const float* invp  = (const float*)(ws + (isA ? WS_INVA : WS_INVB));
  const int f       = isA ? 32 : 48;
  const int kstride = isA ? 32 : 64;
  const int ksteps  = isA ? 1 : 2;

  floatx4 acc1[4][4];
  #pragma unroll
  for (int mt = 0; mt < 4; mt++)
    #pragma unroll
    for (int nt = 0; nt < 4; nt++)
      acc1[mt][nt] = 0.0f;

  for (int kk = 0; kk < ksteps; kk++) {
    short8 bfw[4];
    #pragma unroll
    for (int nt = 0; nt < 4; nt++)
      bfw[nt] = *(const short8*)(weT + (size_t)(64*wave + 16*nt + l15) * kstride + kk*32 + quad*8);
    const int k0 = kk*32 + quad*8;
    const bool kvalid = (k0 < f);
    floatx4 mv0 = {0,0,0,0}, mv1 = {0,0,0,0}, iv0 = {1,1,1,1}, iv1 = {1,1,1,1};
    if (kvalid) {
      mv0 = *(const floatx4*)(meanp + k0);  mv1 = *(const floatx4*)(meanp + k0 + 4);
      iv0 = *(const floatx4*)(invp + k0);   iv1 = *(const floatx4*)(invp + k0 + 4);
    }
    #pragma unroll
    for (int mt = 0; mt < 4; mt++) {
      short8 a = {0,0,0,0,0,0,0,0};
      int row = 16*mt + l15;
      if (kvalid && row < valid) {
        const float* fp = feats + (size_t)(r0 + row) * f + k0;
        floatx4 x0 = *(const floatx4*)fp;
        floatx4 x1 = *(const floatx4*)(fp + 4);
        #pragma unroll
        for (int e = 0; e < 4; e++) {
          float h0 = (x0[e] - mv0[e]) * iv0[e];
          h0 = fminf(fmaxf(h0, -5.0f), 5.0f);
          a[e] = f2bf(h0);
          float h1 = (x1[e] - mv1[e]) * iv1[e];
          h1 = fminf(fmaxf(h1, -5.0f), 5.0f);
          a[4+e] = f2bf(h1);
        }
      }
      #pragma unroll
      for (int nt = 0; nt < 4; nt++)
        acc1[mt][nt] = __builtin_amdgcn_mfma_f32_16x16x32_bf16(bfw[nt], a, acc1[mt][nt], 0, 0, 0);
    }
  }

  float sacc[4] = {0.f,0.f,0.f,0.f}, s2acc[4] = {0.f,0.f,0.f,0.f};
  #pragma unroll
  for (int nt = 0; nt < 4; nt++) {
    const int c0 = 64*wave + 16*nt + 4*quad;
    floatx4 b1v = *(const floatx4*)(biasp + c0);
    #pragma unroll
    for (int mt = 0; mt < 4; mt++) {
      short4v pk;
      #pragma unroll
      for (int r = 0; r < 4; r++) {
        float h = fmaxf(acc1[mt][nt][r] + b1v[r], 0.0f);
        sacc[mt] += h;
        s2acc[mt] = fmaf(h, h, s2acc[mt]);
        pk[r] = f2bf(h);
      }
      *(short4v*)(ztile + (16*mt + l15)*264 + c0) = pk;
    }
  }
  #pragma unroll
  for (int mt = 0; mt < 4; mt++) {
    float s = sacc[mt], s2 = s2acc[mt];
    s += __shfl_xor(s, 16, 64);  s2 += __shfl_xor(s2, 16, 64);
    s += __shfl_xor(s, 32, 64);  s2 += __shfl_xor(s2, 32, 64);
    if (lane < 16) {
      sred[16*mt + lane][wave] = s;
      s2red[16*mt + lane][wave] = s2;
    }
  }
  __syncthreads();

  floatx4 acc2[4][4];
  #pragma unroll
  for (int mt = 0; mt < 4; mt++)
    #pragma unroll
    for (int nt = 0; nt < 4; nt++)
      acc2[mt][nt] = 0.0f;
  #pragma unroll 2
  for (int kk = 0; kk < 8; kk++) {
    short8 bf[4];
    #pragma unroll
    for (int nt = 0; nt < 4; nt++)
      bf[nt] = *(const short8*)(w2gT + (size_t)(64*wave + 16*nt + l15)*256 + kk*32 + quad*8);
    #pragma unroll
    for (int mt = 0; mt < 4; mt++) {
      short8 a = *(const short8*)(ztile + (16*mt + l15)*264 + kk*32 + quad*8);
      #pragma unroll
      for (int nt = 0; nt < 4; nt++)
        acc2[mt][nt] = __builtin_amdgcn_mfma_f32_16x16x32_bf16(bf[nt], a, acc2[mt][nt], 0, 0, 0);
    }
  }

  float rsv[4], mrsv[4];
  #pragma unroll
  for (int mt = 0; mt < 4; mt++) {
    int row = 16*mt + l15;
    floatx4 sv  = *(const floatx4*)sred[row];
    floatx4 s2v = *(const floatx4*)s2red[row];
    float s  = sv[0] + sv[1] + sv[2] + sv[3];
    float s2 = s2v[0] + s2v[1] + s2v[2] + s2v[3];
    float mu  = s * (1.0f/256.0f);
    float var = fmaxf(s2 * (1.0f/256.0f) - mu*mu, 0.0f);
    float rs  = rsqrtf(var + 1e-5f);
    rsv[mt]  = rs;
    mrsv[mt] = mu * rs;
  }

  float pv[4] = {0.f, 0.f, 0.f, 0.f};
  #pragma unroll
  for (int nt = 0; nt < 4; nt++) {
    const int c0 = 64*wave + 16*nt + 4*quad;
    floatx4 c1v = *(const floatx4*)(c1p + c0);
    floatx4 c2v = *(const floatx4*)(c2p + c0);
    floatx4 wvv = *(const floatx4*)(Wv + c0);
    #pragma unroll
    for (int mt = 0; mt < 4; mt++) {
      float rs = rsv[mt], mrs = mrsv[mt];
      #pragma unroll
      for (int r = 0; r < 4; r++) {
        float t = fmaf(-mrs, c1v[r], c2v[r]);
        float y = fmaf(rs, acc2[mt][nt][r], t);
        y = fmaxf(y, 0.0f);
        pv[mt] = fmaf(y, wvv[r], pv[mt]);
      }
    }
  }
  #pragma unroll
  for (int mt = 0; mt < 4; mt++) {
    float p = pv[mt];
    p += __shfl_xor(p, 16, 64);
    p += __shfl_xor(p, 32, 64);
    if (lane < 16) vpw[16*mt + lane][wave] = p;
  }
  __syncthreads();

  if (tid < valid) {
    floatx4 vv = *(const floatx4*)vpw[tid];
    float v = vv[0] + vv[1] + vv[2] + vv[3];
    int seg = bidx[gbase + tid];
    atomicAdd(&vpart[split*NSEG + seg], v);
    atomicAdd(&cpart[split*NSEG + seg], 1.0f);
  }
}

__global__ void final_kernel(const float* __restrict__ vpart, const float* __restrict__ cpart,
                             const float* __restrict__ bv, float* __restrict__ out, int nseg) {
  int s = blockIdx.x * blockDim.x + threadIdx.x;
  if (s < nseg) {
    float a = 0.0f, c = 0.0f;
    #pragma unroll 8
    for (int i = 0; i < NSPLIT; i++) { a += vpart[i*NSEG + s]; c += cpart[i*NSEG + s]; }
    out[s] = a / fmaxf(c, 1.0f) + bv[0];
  }
}

extern "C" void kernel_launch(void* const* d_in, const int* in_sizes, int n_in,
                              void* d_out, int out_size, void* d_ws, size_t ws_size,
                              hipStream_t stream) {
  const float* featsA = (const float*)d_in[0];
  const float* featsB = (const float*)d_in[1];
  const float* mA     = (const float*)d_in[2];
  const float* sA     = (const float*)d_in[3];
  const float* mB     = (const float*)d_in[4];
  const float* sB     = (const float*)d_in[5];
  const float* WA     = (const float*)d_in[6];
  const float* bA     = (const float*)d_in[7];
  const float* gA     = (const float*)d_in[8];
  const float* betaA  = (const float*)d_in[9];
  const float* WB     = (const float*)d_in[10];
  const float* bB     = (const float*)d_in[11];
  const float* gB     = (const float*)d_in[12];
  const float* betaB  = (const float*)d_in[13];
  const float* Wback  = (const float*)d_in[14];
  const float* bback  = (const float*)d_in[15];
  const float* Wv     = (const float*)d_in[16];
  const float* bv     = (const float*)d_in[17];
  const int*   bidx   = (const int*)d_in[18];

  const int nA = in_sizes[0] / 32;
  const int nB = in_sizes[1] / 48;
  char* ws = (char*)d_ws;
  float* vpart = (float*)(ws + WS_VPART);
  float* cpart = (float*)(ws + WS_CPART);
  float* out = (float*)d_out;

  const int tilesA = (nA + 63) / 64;
  const int tilesB = (nB + 63) / 64;
  const int rowsApad = tilesA * 64;
  const int rowsBpad = tilesB * 64;
  const size_t nfa_off = WS_NF;
  const size_t nfb_off = nfa_off + (size_t)rowsApad * 32 * 2;
  const size_t ws_need = nfb_off + (size_t)rowsBpad * 64 * 2;
  const bool pre = (ws_size >= ws_need);
  short* nfA = (short*)(ws + nfa_off);
  short* nfB = (short*)(ws + nfb_off);

  const int chunks = rowsApad * 4 + rowsBpad * 8;
  int nblk = (chunks + 255) / 256;
  if (nblk > 2048) nblk = 2048;
  prep_norm_kernel<<<nblk, 256, 0, stream>>>(
      featsA, featsB, mA, mB, sA, sB, WA, WB, Wback, gA, betaA, gB, betaB,
      bback, ws, nfA, nfB, rowsApad, nA, rowsBpad, nB);

  if (pre) {
    fused_kernel<true><<<tilesA + tilesB, 256, 0, stream>>>(
        featsA, featsB, nfA, nfB, mA, mB, bA, bB, Wv, bidx, ws, vpart, cpart,
        tilesA, nA, nB);
  } else {
    fused_kernel<false><<<tilesA + tilesB, 256, 0, stream>>>(
        featsA, featsB, nfA, nfB, mA, mB, bA, bB, Wv, bidx, ws, vpart, cpart,
        tilesA, nA, nB);
  }

  if (out_size > 0)
    final_kernel<<<(out_size + 255) / 256, 256, 0, stream>>>(vpart, cpart, bv, out, out_size);
}

// Round 8
// 301.468 us; speedup vs baseline: 1.0456x; 1.0456x over previous
//
#include <hip/hip_runtime.h>

#define NSEG 512
#define NSPLIT 32

typedef __attribute__((ext_vector_type(8))) short short8;
typedef __attribute__((ext_vector_type(4))) short short4v;
typedef __attribute__((ext_vector_type(4))) float floatx4;

// ws layout (bytes), all 16B-aligned
#define WS_WAT   0        // short [256][32]   WA^T
#define WS_WBT2  16384    // short [256][64]   WB^T (K padded 48->64 w/ zeros)
#define WS_W2GA  49152    // short [256][256]  (gA*Wback)^T
#define WS_W2GB  180224   // short [256][256]  (gB*Wback)^T
#define WS_C1A   311296   // float[256] gA . Wback[:,n]
#define WS_C2A   312320   // float[256] betaA . Wback[:,n] + bback
#define WS_C1B   313344
#define WS_C2B   314368
#define WS_INVA  315392   // float[32]  1/stdA
#define WS_INVB  315520   // float[48]  1/stdB
#define WS_VPART 315712   // float [NSPLIT][NSEG]
#define WS_CPART 381248   // float [NSPLIT][NSEG]
#define WS_NF    446848   // bf16 normalized feats (A then B), if ws_size permits

__device__ __forceinline__ short f2bf(float f) {  // RNE
  unsigned u = __builtin_bit_cast(unsigned, f);
  u += 0x7FFFu + ((u >> 16) & 1u);
  return (short)(u >> 16);
}

// ---- merged prep + norm: one launch. Tables/c1c2/zeroing ride along with the
// streaming normalization (norm dominates; prep work is ~7% extra chunks).
__global__ __launch_bounds__(256) void prep_norm_kernel(
    const float* __restrict__ fA, const float* __restrict__ fB,
    const float* __restrict__ mA, const float* __restrict__ mB,
    const float* __restrict__ sA, const float* __restrict__ sB,
    const float* __restrict__ WA, const float* __restrict__ WB,
    const float* __restrict__ Wback,
    const float* __restrict__ gA, const float* __restrict__ betaA,
    const float* __restrict__ gB, const float* __restrict__ betaB,
    const float* __restrict__ bback,
    char* __restrict__ ws, short* __restrict__ nfA, short* __restrict__ nfB,
    int rowsApad, int nA, int rowsBpad, int nB)
{
  __shared__ float sinv[80];            // [0:32) 1/stdA, [32:80) 1/stdB
  if (threadIdx.x < 32) sinv[threadIdx.x] = 1.0f / sA[threadIdx.x];
  else if (threadIdx.x < 80) sinv[threadIdx.x] = 1.0f / sB[threadIdx.x - 32];
  __syncthreads();
  const float* invAl = sinv;
  const float* invBl = sinv + 32;

  int tid = blockIdx.x * blockDim.x + threadIdx.x;
  int stride = gridDim.x * blockDim.x;

  // c1/c2 (blocks 0..3, one coefficient vector each; overlapped with norm elsewhere)
  if (blockIdx.x < 4) {
    int n = threadIdx.x;
    int which = blockIdx.x;
    const float* coef = (which == 0) ? gA : (which == 1) ? betaA : (which == 2) ? gB : betaB;
    float a = 0.f;
    #pragma unroll 8
    for (int k = 0; k < 256; k++) a = fmaf(coef[k], Wback[k*256 + n], a);
    float* dst = (float*)(ws + ((which == 0) ? WS_C1A : (which == 1) ? WS_C2A
                               : (which == 2) ? WS_C1B : WS_C2B));
    dst[n] = a + ((which & 1) ? bback[n] : 0.0f);
  }

  // small tables + zeroing (grid-stride)
  {
    short* waT  = (short*)(ws + WS_WAT);
    short* wbT2 = (short*)(ws + WS_WBT2);
    short* w2gA = (short*)(ws + WS_W2GA);
    short* w2gB = (short*)(ws + WS_W2GB);
    float* invA = (float*)(ws + WS_INVA);
    float* invB = (float*)(ws + WS_INVB);
    float* vz   = (float*)(ws + WS_VPART);
    if (tid < 32) invA[tid] = invAl[tid];
    if (tid < 48) invB[tid] = invBl[tid];
    for (int i = tid; i < 32*256; i += stride) {          // waT[n][k] = WA[k][n]
      int n = i >> 5, k = i & 31;
      waT[i] = f2bf(WA[k*256 + n]);
    }
    for (int i = tid; i < 256*64; i += stride) {          // wbT2[n][k] = WB[k][n], pad K
      int n = i >> 6, k = i & 63;
      wbT2[i] = (k < 48) ? f2bf(WB[k*256 + n]) : (short)0;
    }
    for (int i = tid; i < 256*256; i += stride) {         // w2g[n][k] = g[k]*Wback[k][n]
      int n = i >> 8, k = i & 255;
      float w = Wback[k*256 + n];
      w2gA[i] = f2bf(gA[k] * w);
      w2gB[i] = f2bf(gB[k] * w);
    }
    for (int i = tid; i < 2*NSPLIT*NSEG; i += stride) vz[i] = 0.0f;
  }

  // streaming normalization: nf = bf16(clamp((x-mean)*inv)), zero-padded
  int chunksA = rowsApad * 4;   // 4 x 8-elem chunks per 32-wide row
  int chunksB = rowsBpad * 8;   // 8 x 8-elem chunks per 64-wide row
  for (int i = tid; i < chunksA + chunksB; i += stride) {
    short8 o = {0,0,0,0,0,0,0,0};
    if (i < chunksA) {
      int row = i >> 2, c0 = (i & 3) * 8;
      if (row < nA) {
        const float* fp = fA + (size_t)row*32 + c0;
        floatx4 x0 = *(const floatx4*)fp;
        floatx4 x1 = *(const floatx4*)(fp + 4);
        floatx4 mv0 = *(const floatx4*)(mA + c0);
        floatx4 mv1 = *(const floatx4*)(mA + c0 + 4);
        floatx4 iv0 = *(const floatx4*)(invAl + c0);
        floatx4 iv1 = *(const floatx4*)(invAl + c0 + 4);
        #pragma unroll
        for (int e = 0; e < 4; e++) {
          float h0 = fminf(fmaxf((x0[e] - mv0[e]) * iv0[e], -5.0f), 5.0f);
          float h1 = fminf(fmaxf((x1[e] - mv1[e]) * iv1[e], -5.0f), 5.0f);
          o[e] = f2bf(h0);  o[4+e] = f2bf(h1);
        }
      }
      *(short8*)(nfA + (size_t)row*32 + c0) = o;
    } else {
      int j = i - chunksA;
      int row = j >> 3, c0 = (j & 7) * 8;
      if (row < nB && c0 < 48) {
        const float* fp = fB + (size_t)row*48 + c0;
        floatx4 x0 = *(const floatx4*)fp;
        floatx4 x1 = *(const floatx4*)(fp + 4);
        floatx4 mv0 = *(const floatx4*)(mB + c0);
        floatx4 mv1 = *(const floatx4*)(mB + c0 + 4);
        floatx4 iv0 = *(const floatx4*)(invBl + c0);
        floatx4 iv1 = *(const floatx4*)(invBl + c0 + 4);
        #pragma unroll
        for (int e = 0; e < 4; e++) {
          float h0 = fminf(fmaxf((x0[e] - mv0[e]) * iv0[e], -5.0f), 5.0f);
          float h1 = fminf(fmaxf((x1[e] - mv1[e]) * iv1[e], -5.0f), 5.0f);
          o[e] = f2bf(h0);  o[4+e] = f2bf(h1);
        }
      }
      *(short8*)(nfB + (size_t)row*64 + c0) = o;
    }
  }
}

// 256 threads / 4 waves; wave owns cols [64w, 64w+64) of a 64-row tile.
// acc[4][4] = 64 AGPRs. REGISTER TIER: (256,3) -> 170 total regs, so
// 64 AGPR + ~100 VGPR fit with NO scratch spill. Every (256,4) variant
// (rounds 1-6) spilled 22-68 MB to scratch because 64 arch VGPRs can't hold
// the GEMM live set; round-6 asm-level restructuring made it WORSE.
// Occupancy drops 16 -> 12 waves/CU; spill traffic+latency disappears.
// (Resubmission of round-7 source: that bench died to container acquisition,
// same as round 4 -> round 5 resubmit which then passed.)
// Operand-swapped MFMA: mfma(W_frag, h_frag) => lane's 4 acc regs are 4
// CONSECUTIVE cols of one row: row = 16*mt + l15, col = 64*w + 16*nt + 4*quad + r.
template <bool PRE>
__global__ __launch_bounds__(256, 3) void fused_kernel(
    const float* __restrict__ featsA, const float* __restrict__ featsB,
    const short* __restrict__ nfA, const short* __restrict__ nfB,
    const float* __restrict__ mA, const float* __restrict__ mB,
    const float* __restrict__ bA, const float* __restrict__ bB,
    const float* __restrict__ Wv, const int* __restrict__ bidx,
    const char* __restrict__ ws, float* __restrict__ vpart, float* __restrict__ cpart,
    int tilesA, int nA, int nB)
{
  __shared__ __attribute__((aligned(16))) short ztile[64*264];   // h, bf16, stride 264
  __shared__ __attribute__((aligned(16))) float sred[64][4];
  __shared__ __attribute__((aligned(16))) float s2red[64][4];
  __shared__ __attribute__((aligned(16))) float vpw[64][4];

  const int tid  = threadIdx.x;
  const int wave = tid >> 6;
  const int lane = tid & 63;
  const int l15  = lane & 15;
  const int quad = lane >> 4;

  const bool isA = (blockIdx.x < (unsigned)tilesA);
  const int  tb  = isA ? blockIdx.x : (blockIdx.x - tilesA);
  const int  r0  = tb * 64;
  const int  nrows = isA ? nA : nB;
  const int  valid = min(64, nrows - r0);
  const int  gbase = (isA ? r0 : (nA + r0));
  const int  split = blockIdx.x & (NSPLIT - 1);
  const float* feats = isA ? featsA : featsB;
  const short* nf    = isA ? nfA : nfB;
  const float* meanp = isA ? mA : mB;
  const float* invp  = (const float*)(ws + (isA ? WS_INVA : WS_INVB));
  const float* biasp = isA ? bA : bB;
  const short* weT   = (const short*)(ws + (isA ? WS_WAT : WS_WBT2));
  const short* w2gT  = (const short*)(ws + (isA ? WS_W2GA : WS_W2GB));
  const float* c1p   = (const float*)(ws + (isA ? WS_C1A : WS_C1B));
  const float* c2p   = (const float*)(ws + (isA ? WS_C2A : WS_C2B));
  const int f       = isA ? 32 : 48;
  const int kstride = isA ? 32 : 64;
  const int ksteps  = isA ? 1 : 2;

  // ---- GEMM1: h = relu(norm(feats) @ W1 + b1) ----
  floatx4 acc1[4][4];
  #pragma unroll
  for (int mt = 0; mt < 4; mt++)
    #pragma unroll
    for (int nt = 0; nt < 4; nt++)
      acc1[mt][nt] = 0.0f;

  for (int kk = 0; kk < ksteps; kk++) {
    short8 bfw[4];
    #pragma unroll
    for (int nt = 0; nt < 4; nt++)
      bfw[nt] = *(const short8*)(weT + (size_t)(64*wave + 16*nt + l15) * kstride + kk*32 + quad*8);

    if (PRE) {
      #pragma unroll
      for (int mt = 0; mt < 4; mt++) {
        short8 a = *(const short8*)(nf + (size_t)(r0 + 16*mt + l15) * kstride + kk*32 + quad*8);
        #pragma unroll
        for (int nt = 0; nt < 4; nt++)
          acc1[mt][nt] = __builtin_amdgcn_mfma_f32_16x16x32_bf16(bfw[nt], a, acc1[mt][nt], 0, 0, 0);
      }
    } else {
      const int k0 = kk*32 + quad*8;
      const bool kvalid = (k0 < f);
      floatx4 mv0 = {0,0,0,0}, mv1 = {0,0,0,0}, iv0 = {1,1,1,1}, iv1 = {1,1,1,1};
      if (kvalid) {
        mv0 = *(const floatx4*)(meanp + k0);  mv1 = *(const floatx4*)(meanp + k0 + 4);
        iv0 = *(const floatx4*)(invp + k0);   iv1 = *(const floatx4*)(invp + k0 + 4);
      }
      #pragma unroll
      for (int mt = 0; mt < 4; mt++) {
        short8 a = {0,0,0,0,0,0,0,0};
        int row = 16*mt + l15;
        if (kvalid && row < valid) {
          const float* fp = feats + (size_t)(r0 + row) * f + k0;
          floatx4 x0 = *(const floatx4*)fp;
          floatx4 x1 = *(const floatx4*)(fp + 4);
          #pragma unroll
          for (int e = 0; e < 4; e++) {
            float h0 = (x0[e] - mv0[e]) * iv0[e];
            h0 = fminf(fmaxf(h0, -5.0f), 5.0f);
            a[e] = f2bf(h0);
            float h1 = (x1[e] - mv1[e]) * iv1[e];
            h1 = fminf(fmaxf(h1, -5.0f), 5.0f);
            a[4+e] = f2bf(h1);
          }
        }
        #pragma unroll
        for (int nt = 0; nt < 4; nt++)
          acc1[mt][nt] = __builtin_amdgcn_mfma_f32_16x16x32_bf16(bfw[nt], a, acc1[mt][nt], 0, 0, 0);
      }
    }
  }

  // ---- epilogue1: h=relu(.+b1) -> ztile (bf16, b64 packed) + per-row stats ----
  float sacc[4] = {0.f,0.f,0.f,0.f}, s2acc[4] = {0.f,0.f,0.f,0.f};
  #pragma unroll
  for (int nt = 0; nt < 4; nt++) {
    const int c0 = 64*wave + 16*nt + 4*quad;
    floatx4 b1v = *(const floatx4*)(biasp + c0);
    #pragma unroll
    for (int mt = 0; mt < 4; mt++) {
      short4v pk;
      #pragma unroll
      for (int r = 0; r < 4; r++) {
        float h = fmaxf(acc1[mt][nt][r] + b1v[r], 0.0f);
        sacc[mt] += h;
        s2acc[mt] = fmaf(h, h, s2acc[mt]);
        pk[r] = f2bf(h);
      }
      *(short4v*)(ztile + (16*mt + l15)*264 + c0) = pk;
    }
  }
  // reduce stats over the 4 quads (cols); rows are lane-local
  #pragma unroll
  for (int mt = 0; mt < 4; mt++) {
    float s = sacc[mt], s2 = s2acc[mt];
    s += __shfl_xor(s, 16, 64);  s2 += __shfl_xor(s2, 16, 64);
    s += __shfl_xor(s, 32, 64);  s2 += __shfl_xor(s2, 32, 64);
    if (lane < 16) {
      sred[16*mt + lane][wave] = s;
      s2red[16*mt + lane][wave] = s2;
    }
  }
  __syncthreads();

  // ---- GEMM2: q = h @ (g*Wback), K=256 ----
  floatx4 acc2[4][4];
  #pragma unroll
  for (int mt = 0; mt < 4; mt++)
    #pragma unroll
    for (int nt = 0; nt < 4; nt++)
      acc2[mt][nt] = 0.0f;

  #pragma unroll 2
  for (int kk = 0; kk < 8; kk++) {
    short8 bf[4];
    #pragma unroll
    for (int nt = 0; nt < 4; nt++)
      bf[nt] = *(const short8*)(w2gT + (size_t)(64*wave + 16*nt + l15)*256 + kk*32 + quad*8);
    #pragma unroll
    for (int mt = 0; mt < 4; mt++) {
      short8 a = *(const short8*)(ztile + (16*mt + l15)*264 + kk*32 + quad*8);
      #pragma unroll
      for (int nt = 0; nt < 4; nt++)
        acc2[mt][nt] = __builtin_amdgcn_mfma_f32_16x16x32_bf16(bf[nt], a, acc2[mt][nt], 0, 0, 0);
    }
  }

  // ---- per-row LN scalars (after GEMM2, from LDS) ----
  float rsv[4], mrsv[4];
  #pragma unroll
  for (int mt = 0; mt < 4; mt++) {
    int row = 16*mt + l15;
    floatx4 sv  = *(const floatx4*)sred[row];
    floatx4 s2v = *(const floatx4*)s2red[row];
    float s  = sv[0] + sv[1] + sv[2] + sv[3];
    float s2 = s2v[0] + s2v[1] + s2v[2] + s2v[3];
    float mu  = s * (1.0f/256.0f);
    float var = fmaxf(s2 * (1.0f/256.0f) - mu*mu, 0.0f);
    float rs  = rsqrtf(var + 1e-5f);
    rsv[mt]  = rs;
    mrsv[mt] = mu * rs;
  }

  // ---- epilogue2: y = relu(rs*q - mu*rs*c1 + c2); v = y . Wv ----
  float pv[4] = {0.f, 0.f, 0.f, 0.f};
  #pragma unroll
  for (int nt = 0; nt < 4; nt++) {
    const int c0 = 64*wave + 16*nt + 4*quad;
    floatx4 c1v = *(const floatx4*)(c1p + c0);
    floatx4 c2v = *(const floatx4*)(c2p + c0);
    floatx4 wvv = *(const floatx4*)(Wv + c0);
    #pragma unroll
    for (int mt = 0; mt < 4; mt++) {
      float rs = rsv[mt], mrs = mrsv[mt];
      #pragma unroll
      for (int r = 0; r < 4; r++) {
        float t = fmaf(-mrs, c1v[r], c2v[r]);
        float y = fmaf(rs, acc2[mt][nt][r], t);
        y = fmaxf(y, 0.0f);
        pv[mt] = fmaf(y, wvv[r], pv[mt]);
      }
    }
  }
  #pragma unroll
  for (int mt = 0; mt < 4; mt++) {
    float p = pv[mt];
    p += __shfl_xor(p, 16, 64);
    p += __shfl_xor(p, 32, 64);
    if (lane < 16) vpw[16*mt + lane][wave] = p;
  }
  __syncthreads();

  // ---- scatter ----
  if (tid < valid) {
    floatx4 vv = *(const floatx4*)vpw[tid];
    float v = vv[0] + vv[1] + vv[2] + vv[3];
    int seg = bidx[gbase + tid];
    atomicAdd(&vpart[split*NSEG + seg], v);
    atomicAdd(&cpart[split*NSEG + seg], 1.0f);
  }
}

__global__ void final_kernel(const float* __restrict__ vpart, const float* __restrict__ cpart,
                             const float* __restrict__ bv, float* __restrict__ out, int nseg) {
  int s = blockIdx.x * blockDim.x + threadIdx.x;
  if (s < nseg) {
    float a = 0.0f, c = 0.0f;
    #pragma unroll 8
    for (int i = 0; i < NSPLIT; i++) { a += vpart[i*NSEG + s]; c += cpart[i*NSEG + s]; }
    out[s] = a / fmaxf(c, 1.0f) + bv[0];
  }
}

extern "C" void kernel_launch(void* const* d_in, const int* in_sizes, int n_in,
                              void* d_out, int out_size, void* d_ws, size_t ws_size,
                              hipStream_t stream) {
  const float* featsA = (const float*)d_in[0];
  const float* featsB = (const float*)d_in[1];
  const float* mA     = (const float*)d_in[2];
  const float* sA     = (const float*)d_in[3];
  const float* mB     = (const float*)d_in[4];
  const float* sB     = (const float*)d_in[5];
  const float* WA     = (const float*)d_in[6];
  const float* bA     = (const float*)d_in[7];
  const float* gA     = (const float*)d_in[8];
  const float* betaA  = (const float*)d_in[9];
  const float* WB     = (const float*)d_in[10];
  const float* bB     = (const float*)d_in[11];
  const float* gB     = (const float*)d_in[12];
  const float* betaB  = (const float*)d_in[13];
  const float* Wback  = (const float*)d_in[14];
  const float* bback  = (const float*)d_in[15];
  const float* Wv     = (const float*)d_in[16];
  const float* bv     = (const float*)d_in[17];
  const int*   bidx   = (const int*)d_in[18];

  const int nA = in_sizes[0] / 32;
  const int nB = in_sizes[1] / 48;
  char* ws = (char*)d_ws;
  float* vpart = (float*)(ws + WS_VPART);
  float* cpart = (float*)(ws + WS_CPART);
  float* out = (float*)d_out;

  const int tilesA = (nA + 63) / 64;
  const int tilesB = (nB + 63) / 64;
  const int rowsApad = tilesA * 64;
  const int rowsBpad = tilesB * 64;
  const size_t nfa_off = WS_NF;
  const size_t nfb_off = nfa_off + (size_t)rowsApad * 32 * 2;
  const size_t ws_need = nfb_off + (size_t)rowsBpad * 64 * 2;
  const bool pre = (ws_size >= ws_need);
  short* nfA = (short*)(ws + nfa_off);
  short* nfB = (short*)(ws + nfb_off);

  const int chunks = rowsApad * 4 + rowsBpad * 8;
  int nblk = (chunks + 255) / 256;
  if (nblk > 2048) nblk = 2048;
  prep_norm_kernel<<<nblk, 256, 0, stream>>>(
      featsA, featsB, mA, mB, sA, sB, WA, WB, Wback, gA, betaA, gB, betaB,
      bback, ws, nfA, nfB, rowsApad, nA, rowsBpad, nB);

  if (pre) {
    fused_kernel<true><<<tilesA + tilesB, 256, 0, stream>>>(
        featsA, featsB, nfA, nfB, mA, mB, bA, bB, Wv, bidx, ws, vpart, cpart,
        tilesA, nA, nB);
  } else {
    fused_kernel<false><<<tilesA + tilesB, 256, 0, stream>>>(
        featsA, featsB, nfA, nfB, mA, mB, bA, bB, Wv, bidx, ws, vpart, cpart,
        tilesA, nA, nB);
  }

  if (out_size > 0)
    final_kernel<<<(out_size + 255) / 256, 256, 0, stream>>>(vpart, cpart, bv, out, out_size);
}